// Round 14
// baseline (19.879 us; speedup 1.0000x reference)
//
#include <hip/hip_runtime.h>

// Problem constants
#define BB    32
#define N_OPC 512
#define N_MAC 64
#define FF    8
#define HH    128
#define OO    8
#define TM    32      // rows per block
#define ASTRB 136     // activation plane row stride (ushorts), 272B

typedef _Float16 f16x8 __attribute__((ext_vector_type(8)));
typedef _Float16 f16x4 __attribute__((ext_vector_type(4)));
typedef float    f32x4 __attribute__((ext_vector_type(4)));

__device__ __forceinline__ float elu_f(float x) {
    return x > 0.0f ? x : (__expf(x) - 1.0f);
}
__device__ __forceinline__ void store_f16(float v, ushort* dst, int off) {
    const _Float16 h = (_Float16)v;
    dst[off] = __builtin_bit_cast(ushort, h);
}
// gather one MFMA A-fragment (weights-as-A swapped form) straight from fp32 W:
//   elem i = W[kbase+i][j], row-major leading dim ld. Lanes cover 16 consecutive
//   cols (64B segments) x 4 k-octets -> dense segments, L1/L2-hot.
__device__ __forceinline__ f16x8 gather8(const float* __restrict__ w, int kbase, int j, int ld) {
    f16x8 v;
    #pragma unroll
    for (int i = 0; i < 8; ++i)
        v[i] = (_Float16)w[(kbase + i) * ld + j];
    return v;
}

// epilogue: acc (4 consecutive output features) + bias -> elu -> fp16 -> 1x ds_write_b64
__device__ __forceinline__ void epi_store(f32x4 a, const float* __restrict__ bias, int jb,
                                          ushort* __restrict__ dst, int off)
{
    const float4 bb = *(const float4*)(bias + jb);
    f16x4 v;
    v[0] = (_Float16)elu_f(a[0] + bb.x);
    v[1] = (_Float16)elu_f(a[1] + bb.y);
    v[2] = (_Float16)elu_f(a[2] + bb.z);
    v[3] = (_Float16)elu_f(a[3] + bb.w);
    *(f16x4*)(dst + off) = v;
}

__global__ __launch_bounds__(512, 4) void mlps_kernel(
    const int*   __restrict__ adj,
    const float* __restrict__ fop,
    const float* __restrict__ fmab,
    const float* __restrict__ l0w1, const float* __restrict__ l0b1,
    const float* __restrict__ l0w2, const float* __restrict__ l0b2,
    const float* __restrict__ l0w3, const float* __restrict__ l0b3,
    const float* __restrict__ l1w1, const float* __restrict__ l1b1,
    const float* __restrict__ l1w2, const float* __restrict__ l1b2,
    const float* __restrict__ l1w3, const float* __restrict__ l1b3,
    const float* __restrict__ pw1,  const float* __restrict__ pb1,
    const float* __restrict__ pw2,  const float* __restrict__ pb2,
    const float* __restrict__ pw3,  const float* __restrict__ pb3,
    float* __restrict__ out)
{
    __shared__ __align__(16) ushort hbuf[2][TM * ASTRB];   // [br], single fp16 plane
    __shared__ __align__(16) ushort gbuf[2][TM * ASTRB];
    __shared__ __align__(16) ushort xinF[TM * FF];
    __shared__ __align__(16) ushort catF[TM * 16];

    const int tid  = threadIdx.x;
    const int wv   = tid >> 6;
    const int lane = tid & 63;
    const int lrow = lane & 15;       // activation row within tile / weight col
    const int lk   = lane >> 4;       // k-octet / output-feature quad
    const int row0 = blockIdx.x * TM;
    const int b    = row0 / N_OPC;
    const int br   = wv >> 2, jt0 = (wv & 3) * 2;

    // ---- P0 prologue: input-data loads FIRST (VMEM completes in order — these
    //      must not queue behind the ~70 weight-gather loads).
    // br1 waves: fop rows straight into registers (no LDS staging).
    f16x8 X1[2] = {};
    if (br == 1 && lk == 0) {
        #pragma unroll
        for (int rt = 0; rt < 2; ++rt) {
            const float* src = fop + (row0 + rt * 16 + lrow) * FF;
            const float4 f0 = *(const float4*)src;
            const float4 f1 = *(const float4*)(src + 4);
            f16x8 v;
            v[0] = (_Float16)f0.x; v[1] = (_Float16)f0.y;
            v[2] = (_Float16)f0.z; v[3] = (_Float16)f0.w;
            v[4] = (_Float16)f1.x; v[5] = (_Float16)f1.y;
            v[6] = (_Float16)f1.z; v[7] = (_Float16)f1.w;
            X1[rt] = v;
        }
    }
    // br0 waves (tid<256): aggregation with DIRECT global fm reads (2KB, L1-hot,
    //      8-lane address broadcast) — no fmS staging, no extra barrier.
    if (tid < TM * FF) {
        const int r = tid >> 3, f = tid & 7;
        const int* arow = adj + (row0 + r) * N_MAC;
        const float* fmc = fmab + b * N_MAC * FF + f;
        float a = 0.0f;
        #pragma unroll
        for (int m4 = 0; m4 < N_MAC; m4 += 4) {
            const int4 av = *(const int4*)(arow + m4);
            a = fmaf((float)av.x, fmc[(m4 + 0) * FF], a);
            a = fmaf((float)av.y, fmc[(m4 + 1) * FF], a);
            a = fmaf((float)av.z, fmc[(m4 + 2) * FF], a);
            a = fmaf((float)av.w, fmc[(m4 + 3) * FF], a);
        }
        store_f16(a, xinF, tid);
    }

    // ---- weight gathers (issued after input loads): P1 + P2 frags
    const float* w1p = br ? l1w1 : l0w1;
    f16x8 w1f[2] = {};
    if (lk == 0) {
        w1f[0] = gather8(w1p, 0, jt0 * 16 + lrow, HH);
        w1f[1] = gather8(w1p, 0, (jt0 + 1) * 16 + lrow, HH);
    }
    const float* w2p = br ? l1w2 : l0w2;
    f16x8 wf2[2][4];
    #pragma unroll
    for (int jtl = 0; jtl < 2; ++jtl)
        #pragma unroll
        for (int ks = 0; ks < 4; ++ks)
            wf2[jtl][ks] = gather8(w2p, ks * 32 + lk * 8, (jt0 + jtl) * 16 + lrow, HH);
    __syncthreads();

    // ---- P1: input layers (K=8 pad 32): waves 0-3 br0, 4-7 br1; 2 jtiles x 2 rowtiles
    {
        const float* b1 = br ? l1b1 : l0b1;
        f16x8 X[2] = {};
        if (lk == 0) {
            if (br == 0) {
                #pragma unroll
                for (int rt = 0; rt < 2; ++rt)
                    X[rt] = *(const f16x8*)(xinF + (rt * 16 + lrow) * FF);
            } else {
                X[0] = X1[0];
                X[1] = X1[1];
            }
        }
        f32x4 acc[2][2] = {};
        #pragma unroll
        for (int jtl = 0; jtl < 2; ++jtl)
            #pragma unroll
            for (int rt = 0; rt < 2; ++rt)
                acc[jtl][rt] = __builtin_amdgcn_mfma_f32_16x16x32_f16(w1f[jtl], X[rt], acc[jtl][rt], 0, 0, 0);
        #pragma unroll
        for (int jtl = 0; jtl < 2; ++jtl) {
            const int jb = (jt0 + jtl) * 16 + lk * 4;
            #pragma unroll
            for (int rt = 0; rt < 2; ++rt)
                epi_store(acc[jtl][rt], b1, jb, hbuf[br], (rt * 16 + lrow) * ASTRB + jb);
        }
    }
    __syncthreads();

    // ---- gather P3 frags (W3: 128x8, cols lrow<8 valid)
    f16x8 wf3[4] = {};
    if (wv < 4 && lrow < OO) {
        const float* w3p = (wv >> 1) ? l1w3 : l0w3;
        #pragma unroll
        for (int ks = 0; ks < 4; ++ks)
            wf3[ks] = gather8(w3p, ks * 32 + lk * 8, lrow, OO);
    }
    // ---- P2: heavy layers (128x128), frags preloaded
    {
        const ushort* aF = hbuf[br];
        f32x4 acc[2][2] = {};
        #pragma unroll
        for (int ks = 0; ks < 4; ++ks) {
            f16x8 x[2];
            #pragma unroll
            for (int rt = 0; rt < 2; ++rt)
                x[rt] = *(const f16x8*)(aF + (rt * 16 + lrow) * ASTRB + ks * 32 + lk * 8);
            #pragma unroll
            for (int jtl = 0; jtl < 2; ++jtl)
                #pragma unroll
                for (int rt = 0; rt < 2; ++rt)
                    acc[jtl][rt] = __builtin_amdgcn_mfma_f32_16x16x32_f16(wf2[jtl][ks], x[rt], acc[jtl][rt], 0, 0, 0);
        }
        const float* b2 = br ? l1b2 : l0b2;
        #pragma unroll
        for (int jtl = 0; jtl < 2; ++jtl) {
            const int jb = (jt0 + jtl) * 16 + lk * 4;
            #pragma unroll
            for (int rt = 0; rt < 2; ++rt)
                epi_store(acc[jtl][rt], b2, jb, gbuf[br], (rt * 16 + lrow) * ASTRB + jb);
        }
    }
    __syncthreads();

    // ---- gather P4 frag (pw1, K=16 -> lk<2 rows)
    f16x8 wf4 = {};
    if (lk < 2)
        wf4 = gather8(pw1, lk * 8, wv * 16 + lrow, HH);
    // ---- P3: branch output layers (128 -> 8 pad 16): waves 0-3
    if (wv < 4) {
        const int br3 = wv >> 1, rt = wv & 1;
        const ushort* aF = gbuf[br3];
        f32x4 acc = {};
        #pragma unroll
        for (int ks = 0; ks < 4; ++ks) {
            const f16x8 x = *(const f16x8*)(aF + (rt * 16 + lrow) * ASTRB + ks * 32 + lk * 8);
            acc = __builtin_amdgcn_mfma_f32_16x16x32_f16(wf3[ks], x, acc, 0, 0, 0);
        }
        if (lk < 2) {
            const float* b3 = br3 ? l1b3 : l0b3;
            epi_store(acc, b3, lk * 4, catF, (rt * 16 + lrow) * 16 + br3 * OO + lk * 4);
        }
    }
    __syncthreads();

    // ---- gather P5 frags (pw2)
    f16x8 wf5[4];
    #pragma unroll
    for (int ks = 0; ks < 4; ++ks)
        wf5[ks] = gather8(pw2, ks * 32 + lk * 8, wv * 16 + lrow, HH);
    // ---- P4: proj input layer (K=16 pad 32): wave wv -> jtile wv, 2 rowtiles
    {
        f16x8 X[2] = {};
        if (lk < 2) {
            #pragma unroll
            for (int rt = 0; rt < 2; ++rt)
                X[rt] = *(const f16x8*)(catF + (rt * 16 + lrow) * 16 + lk * 8);
        }
        f32x4 acc[2] = {};
        #pragma unroll
        for (int rt = 0; rt < 2; ++rt)
            acc[rt] = __builtin_amdgcn_mfma_f32_16x16x32_f16(wf4, X[rt], acc[rt], 0, 0, 0);
        const int jb = wv * 16 + lk * 4;
        #pragma unroll
        for (int rt = 0; rt < 2; ++rt)
            epi_store(acc[rt], pb1, jb, hbuf[0], (rt * 16 + lrow) * ASTRB + jb);
    }
    __syncthreads();

    // ---- gather P6 frags (pw3)
    f16x8 wf6[4] = {};
    if (wv < 2 && lrow < OO) {
        #pragma unroll
        for (int ks = 0; ks < 4; ++ks)
            wf6[ks] = gather8(pw3, ks * 32 + lk * 8, lrow, OO);
    }
    // ---- P5: proj heavy layer (128x128): wave wv -> jtile wv, 2 rowtiles
    {
        const ushort* aF = hbuf[0];
        f32x4 acc[2] = {};
        #pragma unroll
        for (int ks = 0; ks < 4; ++ks) {
            #pragma unroll
            for (int rt = 0; rt < 2; ++rt) {
                const f16x8 x = *(const f16x8*)(aF + (rt * 16 + lrow) * ASTRB + ks * 32 + lk * 8);
                acc[rt] = __builtin_amdgcn_mfma_f32_16x16x32_f16(wf5[ks], x, acc[rt], 0, 0, 0);
            }
        }
        const int jb = wv * 16 + lk * 4;
        #pragma unroll
        for (int rt = 0; rt < 2; ++rt)
            epi_store(acc[rt], pb2, jb, gbuf[0], (rt * 16 + lrow) * ASTRB + jb);
    }
    __syncthreads();

    // ---- P6: proj output layer (128 -> 8): waves 0,1 -> rowtiles, dwordx4 store
    if (wv < 2) {
        const int rt = wv;
        const ushort* aF = gbuf[0];
        f32x4 acc = {};
        #pragma unroll
        for (int ks = 0; ks < 4; ++ks) {
            const f16x8 x = *(const f16x8*)(aF + (rt * 16 + lrow) * ASTRB + ks * 32 + lk * 8);
            acc = __builtin_amdgcn_mfma_f32_16x16x32_f16(wf6[ks], x, acc, 0, 0, 0);
        }
        if (lk < 2) {
            const float4 bb = *(const float4*)(pb3 + lk * 4);
            float4 o;
            o.x = acc[0] + bb.x; o.y = acc[1] + bb.y;
            o.z = acc[2] + bb.z; o.w = acc[3] + bb.w;
            *(float4*)(out + (row0 + rt * 16 + lrow) * OO + lk * 4) = o;
        }
    }
}

extern "C" void kernel_launch(void* const* d_in, const int* in_sizes, int n_in,
                              void* d_out, int out_size, void* d_ws, size_t ws_size,
                              hipStream_t stream) {
    (void)in_sizes; (void)n_in; (void)out_size; (void)d_ws; (void)ws_size;
    const int*   adj  = (const int*)  d_in[0];
    const float* fop  = (const float*)d_in[1];
    const float* fmab = (const float*)d_in[2];
    const float* l0w1 = (const float*)d_in[3];
    const float* l0b1 = (const float*)d_in[4];
    const float* l0w2 = (const float*)d_in[5];
    const float* l0b2 = (const float*)d_in[6];
    const float* l0w3 = (const float*)d_in[7];
    const float* l0b3 = (const float*)d_in[8];
    const float* l1w1 = (const float*)d_in[9];
    const float* l1b1 = (const float*)d_in[10];
    const float* l1w2 = (const float*)d_in[11];
    const float* l1b2 = (const float*)d_in[12];
    const float* l1w3 = (const float*)d_in[13];
    const float* l1b3 = (const float*)d_in[14];
    const float* pw1  = (const float*)d_in[15];
    const float* pb1  = (const float*)d_in[16];
    const float* pw2  = (const float*)d_in[17];
    const float* pb2  = (const float*)d_in[18];
    const float* pw3  = (const float*)d_in[19];
    const float* pb3  = (const float*)d_in[20];
    float* out = (float*)d_out;

    const int grid = (BB * N_OPC) / TM;   // 512
    mlps_kernel<<<dim3(grid), dim3(512), 0, stream>>>(
        adj, fop, fmab,
        l0w1, l0b1, l0w2, l0b2, l0w3, l0b3,
        l1w1, l1b1, l1w2, l1b2, l1w3, l1b3,
        pw1, pb1, pw2, pb2, pw3, pb3,
        out);
}

// Round 15
// 19.446 us; speedup vs baseline: 1.0223x; 1.0223x over previous
//
#include <hip/hip_runtime.h>

// Problem constants
#define BB    32
#define N_OPC 512
#define N_MAC 64
#define FF    8
#define HH    128
#define OO    8
#define TM    32      // rows per block
#define ASTRB 136     // activation plane row stride (ushorts), 272B

typedef _Float16 f16x8 __attribute__((ext_vector_type(8)));
typedef _Float16 f16x4 __attribute__((ext_vector_type(4)));
typedef float    f32x4 __attribute__((ext_vector_type(4)));

__device__ __forceinline__ float elu_f(float x) {
    return x > 0.0f ? x : (__expf(x) - 1.0f);
}
__device__ __forceinline__ void store_f16(float v, ushort* dst, int off) {
    const _Float16 h = (_Float16)v;
    dst[off] = __builtin_bit_cast(ushort, h);
}
// gather one MFMA A-fragment (weights-as-A swapped form) straight from fp32 W:
//   elem i = W[kbase+i][j], row-major leading dim ld. Lanes cover 16 consecutive
//   cols (64B segments) x 4 k-octets -> dense segments, L1/L2-hot.
__device__ __forceinline__ f16x8 gather8(const float* __restrict__ w, int kbase, int j, int ld) {
    f16x8 v;
    #pragma unroll
    for (int i = 0; i < 8; ++i)
        v[i] = (_Float16)w[(kbase + i) * ld + j];
    return v;
}

// epilogue: acc (4 consecutive output features) + bias -> elu -> fp16 -> 1x ds_write_b64
__device__ __forceinline__ void epi_store(f32x4 a, const float* __restrict__ bias, int jb,
                                          ushort* __restrict__ dst, int off)
{
    const float4 bb = *(const float4*)(bias + jb);
    f16x4 v;
    v[0] = (_Float16)elu_f(a[0] + bb.x);
    v[1] = (_Float16)elu_f(a[1] + bb.y);
    v[2] = (_Float16)elu_f(a[2] + bb.z);
    v[3] = (_Float16)elu_f(a[3] + bb.w);
    *(f16x4*)(dst + off) = v;
}

__global__ __launch_bounds__(512, 4) void mlps_kernel(
    const int*   __restrict__ adj,
    const float* __restrict__ fop,
    const float* __restrict__ fmab,
    const float* __restrict__ l0w1, const float* __restrict__ l0b1,
    const float* __restrict__ l0w2, const float* __restrict__ l0b2,
    const float* __restrict__ l0w3, const float* __restrict__ l0b3,
    const float* __restrict__ l1w1, const float* __restrict__ l1b1,
    const float* __restrict__ l1w2, const float* __restrict__ l1b2,
    const float* __restrict__ l1w3, const float* __restrict__ l1b3,
    const float* __restrict__ pw1,  const float* __restrict__ pb1,
    const float* __restrict__ pw2,  const float* __restrict__ pb2,
    const float* __restrict__ pw3,  const float* __restrict__ pb3,
    float* __restrict__ out)
{
    __shared__ __align__(16) ushort hbuf[2][TM * ASTRB];   // [br], single fp16 plane
    __shared__ __align__(16) ushort gbuf[2][TM * ASTRB];
    __shared__ float fmS[N_MAC * FF];
    __shared__ __align__(16) ushort xinF[TM * FF];
    __shared__ __align__(16) ushort catF[TM * 16];

    const int tid  = threadIdx.x;
    const int wv   = tid >> 6;
    const int lane = tid & 63;
    const int lrow = lane & 15;       // activation row within tile / weight col
    const int lk   = lane >> 4;       // k-octet / output-feature quad
    const int row0 = blockIdx.x * TM;
    const int b    = row0 / N_OPC;
    const int br   = wv >> 2, jt0 = (wv & 3) * 2;

    // ---- early gathers (same issue order as r11): P1 + P2 frags
    const float* w1p = br ? l1w1 : l0w1;
    f16x8 w1f[2] = {};
    if (lk == 0) {
        w1f[0] = gather8(w1p, 0, jt0 * 16 + lrow, HH);
        w1f[1] = gather8(w1p, 0, (jt0 + 1) * 16 + lrow, HH);
    }
    const float* w2p = br ? l1w2 : l0w2;
    f16x8 wf2[2][4];
    #pragma unroll
    for (int jtl = 0; jtl < 2; ++jtl)
        #pragma unroll
        for (int ks = 0; ks < 4; ++ks)
            wf2[jtl][ks] = gather8(w2p, ks * 32 + lk * 8, (jt0 + jtl) * 16 + lrow, HH);

    // ---- stage: machine feats into LDS (fp32); br1 op feats straight to registers
    fmS[tid] = fmab[b * N_MAC * FF + tid];
    f16x8 X1[2] = {};
    if (br == 1 && lk == 0) {
        #pragma unroll
        for (int rt = 0; rt < 2; ++rt) {
            const float* src = fop + (row0 + rt * 16 + lrow) * FF;
            const float4 f0 = *(const float4*)src;
            const float4 f1 = *(const float4*)(src + 4);
            f16x8 v;
            v[0] = (_Float16)f0.x; v[1] = (_Float16)f0.y;
            v[2] = (_Float16)f0.z; v[3] = (_Float16)f0.w;
            v[4] = (_Float16)f1.x; v[5] = (_Float16)f1.y;
            v[6] = (_Float16)f1.z; v[7] = (_Float16)f1.w;
            X1[rt] = v;
        }
    }
    __syncthreads();

    // ---- aggregation: xin[r][f] = sum_m adj[r][m] * fm[m][f]  (fmS in LDS)
    if (tid < TM * FF) {
        const int r = tid >> 3, f = tid & 7;
        const int* arow = adj + (row0 + r) * N_MAC;
        float a = 0.0f;
        #pragma unroll
        for (int m4 = 0; m4 < N_MAC; m4 += 4) {
            const int4 av = *(const int4*)(arow + m4);
            a = fmaf((float)av.x, fmS[(m4 + 0) * FF + f], a);
            a = fmaf((float)av.y, fmS[(m4 + 1) * FF + f], a);
            a = fmaf((float)av.z, fmS[(m4 + 2) * FF + f], a);
            a = fmaf((float)av.w, fmS[(m4 + 3) * FF + f], a);
        }
        store_f16(a, xinF, tid);
    }
    __syncthreads();

    // ---- P1: input layers (K=8 pad 32): waves 0-3 br0, 4-7 br1; 2 jtiles x 2 rowtiles
    {
        const float* b1 = br ? l1b1 : l0b1;
        f16x8 X[2] = {};
        if (lk == 0) {
            if (br == 0) {
                #pragma unroll
                for (int rt = 0; rt < 2; ++rt)
                    X[rt] = *(const f16x8*)(xinF + (rt * 16 + lrow) * FF);
            } else {
                X[0] = X1[0];
                X[1] = X1[1];
            }
        }
        f32x4 acc[2][2] = {};
        #pragma unroll
        for (int jtl = 0; jtl < 2; ++jtl)
            #pragma unroll
            for (int rt = 0; rt < 2; ++rt)
                acc[jtl][rt] = __builtin_amdgcn_mfma_f32_16x16x32_f16(w1f[jtl], X[rt], acc[jtl][rt], 0, 0, 0);
        #pragma unroll
        for (int jtl = 0; jtl < 2; ++jtl) {
            const int jb = (jt0 + jtl) * 16 + lk * 4;
            #pragma unroll
            for (int rt = 0; rt < 2; ++rt)
                epi_store(acc[jtl][rt], b1, jb, hbuf[br], (rt * 16 + lrow) * ASTRB + jb);
        }
    }
    __syncthreads();

    // ---- gather P3 frags (W3: 128x8, cols lrow<8 valid)
    f16x8 wf3[4] = {};
    if (wv < 4 && lrow < OO) {
        const float* w3p = (wv >> 1) ? l1w3 : l0w3;
        #pragma unroll
        for (int ks = 0; ks < 4; ++ks)
            wf3[ks] = gather8(w3p, ks * 32 + lk * 8, lrow, OO);
    }
    // ---- P2: heavy layers (128x128), frags preloaded
    {
        const ushort* aF = hbuf[br];
        f32x4 acc[2][2] = {};
        #pragma unroll
        for (int ks = 0; ks < 4; ++ks) {
            f16x8 x[2];
            #pragma unroll
            for (int rt = 0; rt < 2; ++rt)
                x[rt] = *(const f16x8*)(aF + (rt * 16 + lrow) * ASTRB + ks * 32 + lk * 8);
            #pragma unroll
            for (int jtl = 0; jtl < 2; ++jtl)
                #pragma unroll
                for (int rt = 0; rt < 2; ++rt)
                    acc[jtl][rt] = __builtin_amdgcn_mfma_f32_16x16x32_f16(wf2[jtl][ks], x[rt], acc[jtl][rt], 0, 0, 0);
        }
        const float* b2 = br ? l1b2 : l0b2;
        #pragma unroll
        for (int jtl = 0; jtl < 2; ++jtl) {
            const int jb = (jt0 + jtl) * 16 + lk * 4;
            #pragma unroll
            for (int rt = 0; rt < 2; ++rt)
                epi_store(acc[jtl][rt], b2, jb, gbuf[br], (rt * 16 + lrow) * ASTRB + jb);
        }
    }
    __syncthreads();

    // ---- gather P4 frag (pw1, K=16 -> lk<2 rows)
    f16x8 wf4 = {};
    if (lk < 2)
        wf4 = gather8(pw1, lk * 8, wv * 16 + lrow, HH);
    // ---- P3: branch output layers (128 -> 8 pad 16): waves 0-3
    if (wv < 4) {
        const int br3 = wv >> 1, rt = wv & 1;
        const ushort* aF = gbuf[br3];
        f32x4 acc = {};
        #pragma unroll
        for (int ks = 0; ks < 4; ++ks) {
            const f16x8 x = *(const f16x8*)(aF + (rt * 16 + lrow) * ASTRB + ks * 32 + lk * 8);
            acc = __builtin_amdgcn_mfma_f32_16x16x32_f16(wf3[ks], x, acc, 0, 0, 0);
        }
        if (lk < 2) {
            const float* b3 = br3 ? l1b3 : l0b3;
            epi_store(acc, b3, lk * 4, catF, (rt * 16 + lrow) * 16 + br3 * OO + lk * 4);
        }
    }
    __syncthreads();

    // ---- gather P5 frags (pw2)
    f16x8 wf5[4];
    #pragma unroll
    for (int ks = 0; ks < 4; ++ks)
        wf5[ks] = gather8(pw2, ks * 32 + lk * 8, wv * 16 + lrow, HH);
    // ---- P4: proj input layer (K=16 pad 32): wave wv -> jtile wv, 2 rowtiles
    {
        f16x8 X[2] = {};
        if (lk < 2) {
            #pragma unroll
            for (int rt = 0; rt < 2; ++rt)
                X[rt] = *(const f16x8*)(catF + (rt * 16 + lrow) * 16 + lk * 8);
        }
        f32x4 acc[2] = {};
        #pragma unroll
        for (int rt = 0; rt < 2; ++rt)
            acc[rt] = __builtin_amdgcn_mfma_f32_16x16x32_f16(wf4, X[rt], acc[rt], 0, 0, 0);
        const int jb = wv * 16 + lk * 4;
        #pragma unroll
        for (int rt = 0; rt < 2; ++rt)
            epi_store(acc[rt], pb1, jb, hbuf[0], (rt * 16 + lrow) * ASTRB + jb);
    }
    __syncthreads();

    // ---- gather P6 frags (pw3)
    f16x8 wf6[4] = {};
    if (wv < 2 && lrow < OO) {
        #pragma unroll
        for (int ks = 0; ks < 4; ++ks)
            wf6[ks] = gather8(pw3, ks * 32 + lk * 8, lrow, OO);
    }
    // ---- P5: proj heavy layer (128x128): wave wv -> jtile wv, 2 rowtiles
    {
        const ushort* aF = hbuf[0];
        f32x4 acc[2] = {};
        #pragma unroll
        for (int ks = 0; ks < 4; ++ks) {
            #pragma unroll
            for (int rt = 0; rt < 2; ++rt) {
                const f16x8 x = *(const f16x8*)(aF + (rt * 16 + lrow) * ASTRB + ks * 32 + lk * 8);
                acc[rt] = __builtin_amdgcn_mfma_f32_16x16x32_f16(wf5[ks], x, acc[rt], 0, 0, 0);
            }
        }
        const int jb = wv * 16 + lk * 4;
        #pragma unroll
        for (int rt = 0; rt < 2; ++rt)
            epi_store(acc[rt], pb2, jb, gbuf[0], (rt * 16 + lrow) * ASTRB + jb);
    }
    __syncthreads();

    // ---- P6: proj output layer (128 -> 8): waves 0,1 -> rowtiles, dwordx4 store
    if (wv < 2) {
        const int rt = wv;
        const ushort* aF = gbuf[0];
        f32x4 acc = {};
        #pragma unroll
        for (int ks = 0; ks < 4; ++ks) {
            const f16x8 x = *(const f16x8*)(aF + (rt * 16 + lrow) * ASTRB + ks * 32 + lk * 8);
            acc = __builtin_amdgcn_mfma_f32_16x16x32_f16(wf6[ks], x, acc, 0, 0, 0);
        }
        if (lk < 2) {
            const float4 bb = *(const float4*)(pb3 + lk * 4);
            float4 o;
            o.x = acc[0] + bb.x; o.y = acc[1] + bb.y;
            o.z = acc[2] + bb.z; o.w = acc[3] + bb.w;
            *(float4*)(out + (row0 + rt * 16 + lrow) * OO + lk * 4) = o;
        }
    }
}

extern "C" void kernel_launch(void* const* d_in, const int* in_sizes, int n_in,
                              void* d_out, int out_size, void* d_ws, size_t ws_size,
                              hipStream_t stream) {
    (void)in_sizes; (void)n_in; (void)out_size; (void)d_ws; (void)ws_size;
    const int*   adj  = (const int*)  d_in[0];
    const float* fop  = (const float*)d_in[1];
    const float* fmab = (const float*)d_in[2];
    const float* l0w1 = (const float*)d_in[3];
    const float* l0b1 = (const float*)d_in[4];
    const float* l0w2 = (const float*)d_in[5];
    const float* l0b2 = (const float*)d_in[6];
    const float* l0w3 = (const float*)d_in[7];
    const float* l0b3 = (const float*)d_in[8];
    const float* l1w1 = (const float*)d_in[9];
    const float* l1b1 = (const float*)d_in[10];
    const float* l1w2 = (const float*)d_in[11];
    const float* l1b2 = (const float*)d_in[12];
    const float* l1w3 = (const float*)d_in[13];
    const float* l1b3 = (const float*)d_in[14];
    const float* pw1  = (const float*)d_in[15];
    const float* pb1  = (const float*)d_in[16];
    const float* pw2  = (const float*)d_in[17];
    const float* pb2  = (const float*)d_in[18];
    const float* pw3  = (const float*)d_in[19];
    const float* pb3  = (const float*)d_in[20];
    float* out = (float*)d_out;

    const int grid = (BB * N_OPC) / TM;   // 512
    mlps_kernel<<<dim3(grid), dim3(512), 0, stream>>>(
        adj, fop, fmab,
        l0w1, l0b1, l0w2, l0b2, l0w3, l0b3,
        l1w1, l1b1, l1w2, l1b2, l1w3, l1b3,
        pw1, pb1, pw2, pb2, pw3, pb3,
        out);
}

// Round 16
// 17.774 us; speedup vs baseline: 1.1184x; 1.0941x over previous
//
#include <hip/hip_runtime.h>

// Problem constants
#define BB    32
#define N_OPC 512
#define N_MAC 64
#define FF    8
#define HH    128
#define OO    8
#define TM    32      // rows per block
#define ASTRB 136     // activation plane row stride (ushorts), 272B

typedef _Float16 f16x8 __attribute__((ext_vector_type(8)));
typedef _Float16 f16x4 __attribute__((ext_vector_type(4)));
typedef float    f32x4 __attribute__((ext_vector_type(4)));

__device__ __forceinline__ float elu_f(float x) {
    return x > 0.0f ? x : (__expf(x) - 1.0f);
}
__device__ __forceinline__ void store_f16(float v, ushort* dst, int off) {
    const _Float16 h = (_Float16)v;
    dst[off] = __builtin_bit_cast(ushort, h);
}
// gather one MFMA A-fragment (weights-as-A swapped form) straight from fp32 W:
//   elem i = W[kbase+i][j], row-major leading dim ld. Lanes cover 16 consecutive
//   cols (64B segments) x 4 k-octets -> dense segments, L1/L2-hot.
__device__ __forceinline__ f16x8 gather8(const float* __restrict__ w, int kbase, int j, int ld) {
    f16x8 v;
    #pragma unroll
    for (int i = 0; i < 8; ++i)
        v[i] = (_Float16)w[(kbase + i) * ld + j];
    return v;
}

// epilogue: acc (4 consecutive output features) + bias -> elu -> fp16 -> 1x ds_write_b64
__device__ __forceinline__ void epi_store(f32x4 a, const float* __restrict__ bias, int jb,
                                          ushort* __restrict__ dst, int off)
{
    const float4 bb = *(const float4*)(bias + jb);
    f16x4 v;
    v[0] = (_Float16)elu_f(a[0] + bb.x);
    v[1] = (_Float16)elu_f(a[1] + bb.y);
    v[2] = (_Float16)elu_f(a[2] + bb.z);
    v[3] = (_Float16)elu_f(a[3] + bb.w);
    *(f16x4*)(dst + off) = v;
}

__global__ __launch_bounds__(512, 4) void mlps_kernel(
    const int*   __restrict__ adj,
    const float* __restrict__ fop,
    const float* __restrict__ fmab,
    const float* __restrict__ l0w1, const float* __restrict__ l0b1,
    const float* __restrict__ l0w2, const float* __restrict__ l0b2,
    const float* __restrict__ l0w3, const float* __restrict__ l0b3,
    const float* __restrict__ l1w1, const float* __restrict__ l1b1,
    const float* __restrict__ l1w2, const float* __restrict__ l1b2,
    const float* __restrict__ l1w3, const float* __restrict__ l1b3,
    const float* __restrict__ pw1,  const float* __restrict__ pb1,
    const float* __restrict__ pw2,  const float* __restrict__ pb2,
    const float* __restrict__ pw3,  const float* __restrict__ pb3,
    float* __restrict__ out)
{
    __shared__ __align__(16) ushort hbuf[2][TM * ASTRB];   // [br], single fp16 plane
    __shared__ __align__(16) ushort gbuf[2][TM * ASTRB];
    __shared__ float fmS[N_MAC * FF];
    __shared__ __align__(16) ushort xinF[TM * FF];
    __shared__ __align__(16) ushort xopF[TM * FF];
    __shared__ __align__(16) ushort catF[TM * 16];

    const int tid  = threadIdx.x;
    const int wv   = tid >> 6;
    const int lane = tid & 63;
    const int lrow = lane & 15;       // activation row within tile / weight col
    const int lk   = lane >> 4;       // k-octet / output-feature quad
    const int row0 = blockIdx.x * TM;
    const int b    = row0 / N_OPC;
    const int br   = wv >> 2, jt0 = (wv & 3) * 2;

    // ---- early gathers: P1 input-layer frags (K=8 -> lk==0 rows) + P2 heavy frags
    const float* w1p = br ? l1w1 : l0w1;
    f16x8 w1f[2] = {};
    if (lk == 0) {
        w1f[0] = gather8(w1p, 0, jt0 * 16 + lrow, HH);
        w1f[1] = gather8(w1p, 0, (jt0 + 1) * 16 + lrow, HH);
    }
    const float* w2p = br ? l1w2 : l0w2;
    f16x8 wf2[2][4];
    #pragma unroll
    for (int jtl = 0; jtl < 2; ++jtl)
        #pragma unroll
        for (int ks = 0; ks < 4; ++ks)
            wf2[jtl][ks] = gather8(w2p, ks * 32 + lk * 8, (jt0 + jtl) * 16 + lrow, HH);

    // ---- stage: machine feats (fp32), op feats (fp16)
    fmS[tid] = fmab[b * N_MAC * FF + tid];
    if (tid < TM * FF)
        store_f16(fop[row0 * FF + tid], xopF, tid);
    __syncthreads();

    // ---- aggregation: xin[r][f] = sum_m adj[r][m] * fm[m][f]
    if (tid < TM * FF) {
        const int r = tid >> 3, f = tid & 7;
        const int* arow = adj + (row0 + r) * N_MAC;
        float a = 0.0f;
        #pragma unroll
        for (int m4 = 0; m4 < N_MAC; m4 += 4) {
            const int4 av = *(const int4*)(arow + m4);
            a = fmaf((float)av.x, fmS[(m4 + 0) * FF + f], a);
            a = fmaf((float)av.y, fmS[(m4 + 1) * FF + f], a);
            a = fmaf((float)av.z, fmS[(m4 + 2) * FF + f], a);
            a = fmaf((float)av.w, fmS[(m4 + 3) * FF + f], a);
        }
        store_f16(a, xinF, tid);
    }
    __syncthreads();

    // ---- P1: input layers (K=8 pad 32): waves 0-3 br0, 4-7 br1; 2 jtiles x 2 rowtiles
    {
        const ushort* xF = br ? xopF : xinF;
        const float* b1 = br ? l1b1 : l0b1;
        f16x8 X[2] = {};
        if (lk == 0) {
            #pragma unroll
            for (int rt = 0; rt < 2; ++rt)
                X[rt] = *(const f16x8*)(xF + (rt * 16 + lrow) * 8);
        }
        f32x4 acc[2][2] = {};
        #pragma unroll
        for (int jtl = 0; jtl < 2; ++jtl)
            #pragma unroll
            for (int rt = 0; rt < 2; ++rt)
                acc[jtl][rt] = __builtin_amdgcn_mfma_f32_16x16x32_f16(w1f[jtl], X[rt], acc[jtl][rt], 0, 0, 0);
        #pragma unroll
        for (int jtl = 0; jtl < 2; ++jtl) {
            const int jb = (jt0 + jtl) * 16 + lk * 4;
            #pragma unroll
            for (int rt = 0; rt < 2; ++rt)
                epi_store(acc[jtl][rt], b1, jb, hbuf[br], (rt * 16 + lrow) * ASTRB + jb);
        }
    }
    __syncthreads();

    // ---- gather P3 frags (W3: 128x8, cols lrow<8 valid)
    f16x8 wf3[4] = {};
    if (wv < 4 && lrow < OO) {
        const float* w3p = (wv >> 1) ? l1w3 : l0w3;
        #pragma unroll
        for (int ks = 0; ks < 4; ++ks)
            wf3[ks] = gather8(w3p, ks * 32 + lk * 8, lrow, OO);
    }
    // ---- P2: heavy layers (128x128), frags preloaded
    {
        const ushort* aF = hbuf[br];
        f32x4 acc[2][2] = {};
        #pragma unroll
        for (int ks = 0; ks < 4; ++ks) {
            f16x8 x[2];
            #pragma unroll
            for (int rt = 0; rt < 2; ++rt)
                x[rt] = *(const f16x8*)(aF + (rt * 16 + lrow) * ASTRB + ks * 32 + lk * 8);
            #pragma unroll
            for (int jtl = 0; jtl < 2; ++jtl)
                #pragma unroll
                for (int rt = 0; rt < 2; ++rt)
                    acc[jtl][rt] = __builtin_amdgcn_mfma_f32_16x16x32_f16(wf2[jtl][ks], x[rt], acc[jtl][rt], 0, 0, 0);
        }
        const float* b2 = br ? l1b2 : l0b2;
        #pragma unroll
        for (int jtl = 0; jtl < 2; ++jtl) {
            const int jb = (jt0 + jtl) * 16 + lk * 4;
            #pragma unroll
            for (int rt = 0; rt < 2; ++rt)
                epi_store(acc[jtl][rt], b2, jb, gbuf[br], (rt * 16 + lrow) * ASTRB + jb);
        }
    }
    __syncthreads();

    // ---- gather P4 frag (pw1, K=16 -> lk<2 rows)
    f16x8 wf4 = {};
    if (lk < 2)
        wf4 = gather8(pw1, lk * 8, wv * 16 + lrow, HH);
    // ---- P3: branch output layers (128 -> 8 pad 16): waves 0-3
    if (wv < 4) {
        const int br3 = wv >> 1, rt = wv & 1;
        const ushort* aF = gbuf[br3];
        f32x4 acc = {};
        #pragma unroll
        for (int ks = 0; ks < 4; ++ks) {
            const f16x8 x = *(const f16x8*)(aF + (rt * 16 + lrow) * ASTRB + ks * 32 + lk * 8);
            acc = __builtin_amdgcn_mfma_f32_16x16x32_f16(wf3[ks], x, acc, 0, 0, 0);
        }
        if (lk < 2) {
            const float* b3 = br3 ? l1b3 : l0b3;
            epi_store(acc, b3, lk * 4, catF, (rt * 16 + lrow) * 16 + br3 * OO + lk * 4);
        }
    }
    __syncthreads();

    // ---- gather P5 frags (pw2)
    f16x8 wf5[4];
    #pragma unroll
    for (int ks = 0; ks < 4; ++ks)
        wf5[ks] = gather8(pw2, ks * 32 + lk * 8, wv * 16 + lrow, HH);
    // ---- P4: proj input layer (K=16 pad 32): wave wv -> jtile wv, 2 rowtiles
    {
        f16x8 X[2] = {};
        if (lk < 2) {
            #pragma unroll
            for (int rt = 0; rt < 2; ++rt)
                X[rt] = *(const f16x8*)(catF + (rt * 16 + lrow) * 16 + lk * 8);
        }
        f32x4 acc[2] = {};
        #pragma unroll
        for (int rt = 0; rt < 2; ++rt)
            acc[rt] = __builtin_amdgcn_mfma_f32_16x16x32_f16(wf4, X[rt], acc[rt], 0, 0, 0);
        const int jb = wv * 16 + lk * 4;
        #pragma unroll
        for (int rt = 0; rt < 2; ++rt)
            epi_store(acc[rt], pb1, jb, hbuf[0], (rt * 16 + lrow) * ASTRB + jb);
    }
    __syncthreads();

    // ---- gather P6 frags (pw3)
    f16x8 wf6[4] = {};
    if (wv < 2 && lrow < OO) {
        #pragma unroll
        for (int ks = 0; ks < 4; ++ks)
            wf6[ks] = gather8(pw3, ks * 32 + lk * 8, lrow, OO);
    }
    // ---- P5: proj heavy layer (128x128): wave wv -> jtile wv, 2 rowtiles
    {
        const ushort* aF = hbuf[0];
        f32x4 acc[2] = {};
        #pragma unroll
        for (int ks = 0; ks < 4; ++ks) {
            #pragma unroll
            for (int rt = 0; rt < 2; ++rt) {
                const f16x8 x = *(const f16x8*)(aF + (rt * 16 + lrow) * ASTRB + ks * 32 + lk * 8);
                acc[rt] = __builtin_amdgcn_mfma_f32_16x16x32_f16(wf5[ks], x, acc[rt], 0, 0, 0);
            }
        }
        const int jb = wv * 16 + lk * 4;
        #pragma unroll
        for (int rt = 0; rt < 2; ++rt)
            epi_store(acc[rt], pb2, jb, gbuf[0], (rt * 16 + lrow) * ASTRB + jb);
    }
    __syncthreads();

    // ---- P6: proj output layer (128 -> 8): waves 0,1 -> rowtiles, dwordx4 store
    if (wv < 2) {
        const int rt = wv;
        const ushort* aF = gbuf[0];
        f32x4 acc = {};
        #pragma unroll
        for (int ks = 0; ks < 4; ++ks) {
            const f16x8 x = *(const f16x8*)(aF + (rt * 16 + lrow) * ASTRB + ks * 32 + lk * 8);
            acc = __builtin_amdgcn_mfma_f32_16x16x32_f16(wf6[ks], x, acc, 0, 0, 0);
        }
        if (lk < 2) {
            const float4 bb = *(const float4*)(pb3 + lk * 4);
            float4 o;
            o.x = acc[0] + bb.x; o.y = acc[1] + bb.y;
            o.z = acc[2] + bb.z; o.w = acc[3] + bb.w;
            *(float4*)(out + (row0 + rt * 16 + lrow) * OO + lk * 4) = o;
        }
    }
}

extern "C" void kernel_launch(void* const* d_in, const int* in_sizes, int n_in,
                              void* d_out, int out_size, void* d_ws, size_t ws_size,
                              hipStream_t stream) {
    (void)in_sizes; (void)n_in; (void)out_size; (void)d_ws; (void)ws_size;
    const int*   adj  = (const int*)  d_in[0];
    const float* fop  = (const float*)d_in[1];
    const float* fmab = (const float*)d_in[2];
    const float* l0w1 = (const float*)d_in[3];
    const float* l0b1 = (const float*)d_in[4];
    const float* l0w2 = (const float*)d_in[5];
    const float* l0b2 = (const float*)d_in[6];
    const float* l0w3 = (const float*)d_in[7];
    const float* l0b3 = (const float*)d_in[8];
    const float* l1w1 = (const float*)d_in[9];
    const float* l1b1 = (const float*)d_in[10];
    const float* l1w2 = (const float*)d_in[11];
    const float* l1b2 = (const float*)d_in[12];
    const float* l1w3 = (const float*)d_in[13];
    const float* l1b3 = (const float*)d_in[14];
    const float* pw1  = (const float*)d_in[15];
    const float* pb1  = (const float*)d_in[16];
    const float* pw2  = (const float*)d_in[17];
    const float* pb2  = (const float*)d_in[18];
    const float* pw3  = (const float*)d_in[19];
    const float* pb3  = (const float*)d_in[20];
    float* out = (float*)d_out;

    const int grid = (BB * N_OPC) / TM;   // 512
    mlps_kernel<<<dim3(grid), dim3(512), 0, stream>>>(
        adj, fop, fmab,
        l0w1, l0b1, l0w2, l0b2, l0w3, l0b3,
        l1w1, l1b1, l1w2, l1b2, l1w3, l1b3,
        pw1, pb1, pw2, pb2, pw3, pb3,
        out);
}